// Round 8
// baseline (530.760 us; speedup 1.0000x reference)
//
#include <hip/hip_runtime.h>

// WeightedLoss: loss_i = (target_i == 1) ? 1 - sigmoid(pred_i) : 0.1 ; out = mean(loss)
// 1 - sigmoid(x) = 1 / (1 + exp(x))
//
// R5 post-mortem: crash was a register-aliasing bug — "=v" outputs on the
// load asm let the allocator overlap a load destination with `off`; the
// delayed write-back corrupted the address register -> page fault. Fix:
// early-clobber "=&v" on all asm outputs. Pipeline structure unchanged:
// 4-slot ring, 8 dwordx4 loads (8 KB/wave) outstanding, s_waitcnt vmcnt(6)
// retires only the oldest slot; vmcnt never drains to 0 in the hot loop.
// (R6/R7 were GPU-broker timeouts — this source is the unchanged kernel.)

#define BLOCK 256
#define GRID  2048   // 8 blocks/CU

typedef float vf4 __attribute__((ext_vector_type(4)));
typedef int   vi4 __attribute__((ext_vector_type(4)));

__device__ __forceinline__ float loss4(vf4 p, vi4 t) {
    float l0 = (t.x == 1) ? 1.0f / (1.0f + __expf(p.x)) : 0.1f;
    float l1 = (t.y == 1) ? 1.0f / (1.0f + __expf(p.y)) : 0.1f;
    float l2 = (t.z == 1) ? 1.0f / (1.0f + __expf(p.z)) : 0.1f;
    float l3 = (t.w == 1) ? 1.0f / (1.0f + __expf(p.w)) : 0.1f;
    return (l0 + l1) + (l2 + l3);
}

__device__ __forceinline__ void block_reduce_atomic(float acc, float inv_n,
                                                    float* __restrict__ out) {
#pragma unroll
    for (int off = 32; off > 0; off >>= 1)
        acc += __shfl_down(acc, off, 64);
    __shared__ float smem[BLOCK / 64];
    const int lane = threadIdx.x & 63;
    const int wave = threadIdx.x >> 6;
    if (lane == 0) smem[wave] = acc;
    __syncthreads();
    if (threadIdx.x == 0) {
        float bsum = (smem[0] + smem[1]) + (smem[2] + smem[3]);
        atomicAdd(out, bsum * inv_n);
    }
}

// Issue both stream loads for one slot at the current byte offset.
// asm volatile => strictly program-ordered vs other asm volatiles.
// "=&v" (early-clobber) is REQUIRED: destination tuples must not alias any
// input (esp. `off`) because the write-back is asynchronous.
#define LOAD_SLOT(P, T)                                                  \
    asm volatile("global_load_dwordx4 %0, %2, %3\n\t"                    \
                 "global_load_dwordx4 %1, %2, %4"                        \
                 : "=&v"(P), "=&v"(T)                                    \
                 : "v"(off), "s"(pred), "s"(tgt));

// Wait until only N vector-memory ops remain outstanding; the "+v" ties make
// every later read of P/T depend on this wait.
#define WAIT_SLOT(N, P, T)                                               \
    asm volatile("s_waitcnt vmcnt(" #N ")" : "+v"(P), "+v"(T));

// Fast path: iters = n4/(GRID*BLOCK), iters % 4 == 0, iters >= 8.
// steady = iters/4 - 1.
__global__ __launch_bounds__(BLOCK)
void wloss_asm(const float* __restrict__ pred,
               const int*   __restrict__ tgt,
               float* __restrict__ out,
               int steady, unsigned stride_b, float inv_n) {
    unsigned off = (blockIdx.x * BLOCK + threadIdx.x) * 16u;

    vf4 p0, p1, p2, p3;
    vi4 t0, t1, t2, t3;

    // Prologue: fill the 4-slot ring -> 8 dwordx4 loads outstanding.
    LOAD_SLOT(p0, t0) off += stride_b;
    LOAD_SLOT(p1, t1) off += stride_b;
    LOAD_SLOT(p2, t2) off += stride_b;
    LOAD_SLOT(p3, t3) off += stride_b;

    float acc = 0.0f;
    for (int k = 0; k < steady; ++k) {
        WAIT_SLOT(6, p0, t0)            // retire oldest slot only
        acc += loss4(p0, t0);
        LOAD_SLOT(p0, t0) off += stride_b;

        WAIT_SLOT(6, p1, t1)
        acc += loss4(p1, t1);
        LOAD_SLOT(p1, t1) off += stride_b;

        WAIT_SLOT(6, p2, t2)
        acc += loss4(p2, t2);
        LOAD_SLOT(p2, t2) off += stride_b;

        WAIT_SLOT(6, p3, t3)
        acc += loss4(p3, t3);
        LOAD_SLOT(p3, t3) off += stride_b;
    }

    // Drain the ring (8 outstanding at entry).
    WAIT_SLOT(6, p0, t0) acc += loss4(p0, t0);
    WAIT_SLOT(4, p1, t1) acc += loss4(p1, t1);
    WAIT_SLOT(2, p2, t2) acc += loss4(p2, t2);
    WAIT_SLOT(0, p3, t3) acc += loss4(p3, t3);

    block_reduce_atomic(acc, inv_n, out);
}

// Generic fallback for arbitrary n.
__global__ __launch_bounds__(BLOCK)
void wloss_generic(const float* __restrict__ pred,
                   const int*   __restrict__ tgt,
                   float* __restrict__ out,
                   long long n, float inv_n) {
    const long long n4     = n >> 2;
    const long long tid    = (long long)blockIdx.x * blockDim.x + threadIdx.x;
    const long long stride = (long long)gridDim.x * blockDim.x;

    const vf4* p4 = (const vf4*)pred;
    const vi4* t4 = (const vi4*)tgt;

    float acc = 0.0f;
    for (long long i = tid; i < n4; i += stride)
        acc += loss4(p4[i], t4[i]);
    if (blockIdx.x == 0) {
        for (long long i = (n4 << 2) + threadIdx.x; i < n; i += blockDim.x)
            acc += (tgt[i] == 1) ? 1.0f / (1.0f + __expf(pred[i])) : 0.1f;
    }
    block_reduce_atomic(acc, inv_n, out);
}

extern "C" void kernel_launch(void* const* d_in, const int* in_sizes, int n_in,
                              void* d_out, int out_size, void* d_ws, size_t ws_size,
                              hipStream_t stream) {
    const float* pred = (const float*)d_in[0];
    const int*   tgt  = (const int*)d_in[1];
    float*       out  = (float*)d_out;

    const long long n = (long long)in_sizes[0];
    const float inv_n = 1.0f / (float)n;

    hipMemsetAsync(out, 0, sizeof(float), stream);

    const long long n4 = n >> 2;
    const long long stride_f4 = (long long)GRID * BLOCK;   // 2^19 float4/iter
    const long long iters = (n4 > 0 && n4 % stride_f4 == 0) ? n4 / stride_f4 : 0;

    // Byte stride per slot advance: 2^19 * 16 B = 8 MiB; max offset for
    // N=2^26 is 256 MiB — fits unsigned 32-bit voffset.
    if ((n & 3) == 0 && iters >= 8 && (iters & 3) == 0 &&
        (long long)iters * stride_f4 * 16 <= 0x7fffffffLL) {
        const int steady = (int)(iters / 4 - 1);           // 7 for N=2^26
        wloss_asm<<<GRID, BLOCK, 0, stream>>>(pred, tgt, out, steady,
                                              (unsigned)(stride_f4 * 16), inv_n);
    } else {
        long long g = (n4 + BLOCK - 1) / BLOCK;
        if (g > 8192) g = 8192;
        if (g < 1)    g = 1;
        wloss_generic<<<(int)g, BLOCK, 0, stream>>>(pred, tgt, out, n, inv_n);
    }
}

// Round 9
// 481.250 us; speedup vs baseline: 1.1029x; 1.1029x over previous
//
#include <hip/hip_runtime.h>

// WeightedLoss: loss_i = (target_i == 1) ? 1 - sigmoid(pred_i) : 0.1 ; out = mean(loss)
// 1 - sigmoid(x) = 1 / (1 + exp(x))
//
// R8 post-mortem: explicit asm 8-deep vmcnt ring ran correctly and was SLOWER
// than the compiler's depth-2 pipeline (180 vs ~155us). Depth 1/2/4/8 all
// plateau at ~3.0-3.5 TB/s effective read -> per-wave MLP is NOT the limiter.
// R9: best-known structure (R3 depth-2 pipe, 2048 blocks) + nontemporal loads
// (nt bit) on both streams — tests the cache-allocation-policy mechanism:
// 512 MiB streamed per launch thrashes the 4 MiB/XCD L2.

#define BLOCK 256
#define GRID  2048   // 8 blocks/CU

typedef float vf4 __attribute__((ext_vector_type(4)));
typedef int   vi4 __attribute__((ext_vector_type(4)));

__device__ __forceinline__ float loss4(vf4 p, vi4 t) {
    float l0 = (t.x == 1) ? 1.0f / (1.0f + __expf(p.x)) : 0.1f;
    float l1 = (t.y == 1) ? 1.0f / (1.0f + __expf(p.y)) : 0.1f;
    float l2 = (t.z == 1) ? 1.0f / (1.0f + __expf(p.z)) : 0.1f;
    float l3 = (t.w == 1) ? 1.0f / (1.0f + __expf(p.w)) : 0.1f;
    return (l0 + l1) + (l2 + l3);
}

__device__ __forceinline__ void block_reduce_atomic(float acc, float inv_n,
                                                    float* __restrict__ out) {
#pragma unroll
    for (int off = 32; off > 0; off >>= 1)
        acc += __shfl_down(acc, off, 64);
    __shared__ float smem[BLOCK / 64];
    const int lane = threadIdx.x & 63;
    const int wave = threadIdx.x >> 6;
    if (lane == 0) smem[wave] = acc;
    __syncthreads();
    if (threadIdx.x == 0) {
        float bsum = (smem[0] + smem[1]) + (smem[2] + smem[3]);
        atomicAdd(out, bsum * inv_n);
    }
}

// R3 structure exactly, but all stream loads carry the nt (non-temporal) bit.
__global__ __launch_bounds__(BLOCK)
void wloss_nt(const vf4* __restrict__ p4,
              const vi4* __restrict__ t4,
              float* __restrict__ out,
              int iters, int stride, float inv_n) {
    int i = blockIdx.x * BLOCK + threadIdx.x;

    // Prologue: fill two pipeline slots.
    vf4 pA = __builtin_nontemporal_load(&p4[i]);
    vi4 tA = __builtin_nontemporal_load(&t4[i]);
    vf4 pB = __builtin_nontemporal_load(&p4[i + stride]);
    vi4 tB = __builtin_nontemporal_load(&t4[i + stride]);
    int idx = i + 2 * stride;

    float acc = 0.0f;
    for (int k = 0; k < iters - 2; ++k) {
        vf4 pN = __builtin_nontemporal_load(&p4[idx]);
        vi4 tN = __builtin_nontemporal_load(&t4[idx]);
        idx += stride;
        acc += loss4(pA, tA);
        pA = pB; tA = tB;
        pB = pN; tB = tN;
    }
    acc += loss4(pA, tA);
    acc += loss4(pB, tB);

    block_reduce_atomic(acc, inv_n, out);
}

// Generic fallback for arbitrary n.
__global__ __launch_bounds__(BLOCK)
void wloss_generic(const float* __restrict__ pred,
                   const int*   __restrict__ tgt,
                   float* __restrict__ out,
                   long long n, float inv_n) {
    const long long n4     = n >> 2;
    const long long tid    = (long long)blockIdx.x * blockDim.x + threadIdx.x;
    const long long stride = (long long)gridDim.x * blockDim.x;

    const vf4* p4 = (const vf4*)pred;
    const vi4* t4 = (const vi4*)tgt;

    float acc = 0.0f;
    for (long long i = tid; i < n4; i += stride)
        acc += loss4(p4[i], t4[i]);
    if (blockIdx.x == 0) {
        for (long long i = (n4 << 2) + threadIdx.x; i < n; i += blockDim.x)
            acc += (tgt[i] == 1) ? 1.0f / (1.0f + __expf(pred[i])) : 0.1f;
    }
    block_reduce_atomic(acc, inv_n, out);
}

extern "C" void kernel_launch(void* const* d_in, const int* in_sizes, int n_in,
                              void* d_out, int out_size, void* d_ws, size_t ws_size,
                              hipStream_t stream) {
    const float* pred = (const float*)d_in[0];
    const int*   tgt  = (const int*)d_in[1];
    float*       out  = (float*)d_out;

    const long long n = (long long)in_sizes[0];
    const float inv_n = 1.0f / (float)n;

    hipMemsetAsync(out, 0, sizeof(float), stream);

    const long long n4 = n >> 2;
    const long long stride = (long long)GRID * BLOCK;   // 2^19 float4/step

    if ((n & 3) == 0 && n4 % stride == 0 && n4 / stride >= 2) {
        const int iters = (int)(n4 / stride);           // 32 for N=2^26
        wloss_nt<<<GRID, BLOCK, 0, stream>>>((const vf4*)pred,
                                             (const vi4*)tgt, out,
                                             iters, (int)stride, inv_n);
    } else {
        long long g = (n4 + BLOCK - 1) / BLOCK;
        if (g > 8192) g = 8192;
        if (g < 1)    g = 1;
        wloss_generic<<<(int)g, BLOCK, 0, stream>>>(pred, tgt, out, n, inv_n);
    }
}